// Round 1
// baseline (82.870 us; speedup 1.0000x reference)
//
#include <hip/hip_runtime.h>

#define NI 6
#define NM 4
#define NC 7             // N_IN + 1 coeff columns
#define NRULES 4096
#define ROWS_PER_BLOCK 16
#define RULES_PER_TILE 1024
#define RH_PER_TILE 16   // RULES_PER_TILE / 64

// ---------------- main kernel: partial sums per (row, rule-tile) -------------
__global__ __launch_bounds__(256, 4)
void anfis_main(const float* __restrict__ x, const float* __restrict__ a,
                const float* __restrict__ b, const float* __restrict__ c,
                const float* __restrict__ coeff, float* __restrict__ ws) {
    __shared__ float sCT[NC][RULES_PER_TILE];              // 28 KB transposed coeff tile
    __shared__ float sMemb[ROWS_PER_BLOCK][NI][NM];        // 1.5 KB
    __shared__ float sPhi[ROWS_PER_BLOCK][RH_PER_TILE];    // 1 KB
    __shared__ float sPlo[ROWS_PER_BLOCK][64];             // 4 KB

    const int tid = threadIdx.x;
    const int bx = blockIdx.x;
    const int ruleTile = bx & 3;    // 4 rule tiles of 1024 rules
    const int rowTile  = bx >> 2;   // 256 row tiles of 16 rows
    const int row0 = rowTile * ROWS_PER_BLOCK;
    const int ruleBase = ruleTile * RULES_PER_TILE;

    // ---- stage coeff tile, transposed: sCT[i][local_rule] ----
    for (int idx = tid; idx < RULES_PER_TILE * NC; idx += 256) {
        int rr = idx / NC;
        int i  = idx - rr * NC;
        sCT[i][rr] = coeff[(size_t)(ruleBase + rr) * NC + i];
    }

    // ---- membership values: memb = 1/(1 + (((x-c)/a)^2)^b) ----
    for (int idx = tid; idx < ROWS_PER_BLOCK * NI * NM; idx += 256) {
        int row = idx / (NI * NM);
        int rem = idx - row * (NI * NM);
        int j = rem >> 2;   // input index
        int k = rem & 3;    // mf index
        float xv = x[(row0 + row) * NI + j];
        float av = a[j * NM + k];
        float bv = b[j * NM + k];
        float cv = c[j * NM + k];
        float t = (xv - cv) / av;
        float dist = t * t;
        float db = powf(dist, bv);
        sMemb[row][j][k] = 1.0f / (1.0f + db);
    }
    __syncthreads();

    // ---- Phi table: product of membs for inputs 0..2 at this tile's rh ----
    if (tid < ROWS_PER_BLOCK * RH_PER_TILE) {
        int row = tid >> 4;
        int rhl = tid & 15;
        int rh = ruleTile * RH_PER_TILE + rhl;   // global high-digit index, 0..63
        sPhi[row][rhl] = sMemb[row][0][(rh >> 4) & 3] *
                         sMemb[row][1][(rh >> 2) & 3] *
                         sMemb[row][2][rh & 3];
    }
    // ---- Plo table: product of membs for inputs 3..5, indexed by r_lo ----
    for (int idx = tid; idx < ROWS_PER_BLOCK * 64; idx += 256) {
        int row = idx >> 6;
        int t64 = idx & 63;
        sPlo[row][t64] = sMemb[row][3][(t64 >> 4) & 3] *
                         sMemb[row][4][(t64 >> 2) & 3] *
                         sMemb[row][5][t64 & 3];
    }
    __syncthreads();

    const int wave = tid >> 6;
    const int lane = tid & 63;
    const int lw0 = wave * 4;   // 4 rows per wave

    float plo[4];
    float acc[4][8];
    #pragma unroll
    for (int r = 0; r < 4; ++r) {
        plo[r] = sPlo[lw0 + r][lane];
        #pragma unroll
        for (int i = 0; i < 8; ++i) acc[r][i] = 0.0f;
    }

    // ---- hot loop: lane owns rule column r_lo = lane; iterate 16 rh values ----
    #pragma unroll 4
    for (int rhl = 0; rhl < RH_PER_TILE; ++rhl) {
        float cv[NC];
        #pragma unroll
        for (int i = 0; i < NC; ++i) cv[i] = sCT[i][rhl * 64 + lane];
        #pragma unroll
        for (int r = 0; r < 4; ++r) {
            float w = sPhi[lw0 + r][rhl] * plo[r];   // rule firing strength
            acc[r][7] += w;                          // denominator
            #pragma unroll
            for (int i = 0; i < NC; ++i)
                acc[r][i] = fmaf(w, cv[i], acc[r][i]);
        }
    }

    // ---- 64-lane butterfly reduction (compile-time indices only) ----
    #pragma unroll
    for (int r = 0; r < 4; ++r) {
        #pragma unroll
        for (int i = 0; i < 8; ++i) {
            float v = acc[r][i];
            #pragma unroll
            for (int s = 1; s < 64; s <<= 1) v += __shfl_xor(v, s, 64);
            acc[r][i] = v;
        }
    }

    if (lane == 0) {
        #pragma unroll
        for (int r = 0; r < 4; ++r) {
            int row = row0 + lw0 + r;
            #pragma unroll
            for (int i = 0; i < 8; ++i)
                atomicAdd(&ws[row * 8 + i], acc[r][i]);
        }
    }
}

// ---------------- finalize: out = (num . x_plus) / max(den, 1e-12) ----------
__global__ __launch_bounds__(256)
void anfis_finalize(const float* __restrict__ ws, const float* __restrict__ x,
                    float* __restrict__ out, int B) {
    int row = blockIdx.x * blockDim.x + threadIdx.x;
    if (row >= B) return;
    float num = ws[row * 8 + 6];   // bias column (x_plus last element = 1)
    #pragma unroll
    for (int j = 0; j < NI; ++j)
        num = fmaf(ws[row * 8 + j], x[row * NI + j], num);
    float den = ws[row * 8 + 7];
    out[row] = num / fmaxf(den, 1e-12f);
}

extern "C" void kernel_launch(void* const* d_in, const int* in_sizes, int n_in,
                              void* d_out, int out_size, void* d_ws, size_t ws_size,
                              hipStream_t stream) {
    const float* x     = (const float*)d_in[0];
    const float* a     = (const float*)d_in[1];
    const float* b     = (const float*)d_in[2];
    const float* c     = (const float*)d_in[3];
    const float* coeff = (const float*)d_in[4];
    // d_in[5] = mf_indices: full cartesian product in lexicographic order;
    // the factorization Phi (inputs 0-2) x Plo (inputs 3-5) encodes it exactly.
    float* out = (float*)d_out;
    float* ws  = (float*)d_ws;

    const int B = in_sizes[0] / NI;   // 4096

    hipMemsetAsync(ws, 0, (size_t)B * 8 * sizeof(float), stream);

    const int rowTiles = B / ROWS_PER_BLOCK;          // 256
    anfis_main<<<dim3(rowTiles * 4), dim3(256), 0, stream>>>(x, a, b, c, coeff, ws);
    anfis_finalize<<<dim3((B + 255) / 256), dim3(256), 0, stream>>>(ws, x, out, B);
}

// Round 2
// 78.030 us; speedup vs baseline: 1.0620x; 1.0620x over previous
//
#include <hip/hip_runtime.h>

#define NI 6
#define NM 4
#define NC 7               // N_IN + 1 coeff columns
#define ROWS_PER_BLOCK 16
#define RPW 4              // rows per wave (row-group)

// One fused kernel: block = 16 rows x all 4096 rules, writes out directly.
// 512 threads = 8 waves = 4 row-groups x 2 rh-halves.
// Rule r factorizes (lexicographic mf_indices): r = rh*64 + rlo,
//   firing(b,r) = Phi[b,rh] * Plo[b,rlo]
//   Phi = memb0*memb1*memb2 (digits of rh), Plo = memb3*memb4*memb5 (digits of rlo).
// Lane owns rlo = lane; wave half h covers rh in [h*32, h*32+32), 2 staged phases of 16 rh.
__global__ __launch_bounds__(512, 2)
void anfis_fused(const float* __restrict__ x, const float* __restrict__ a,
                 const float* __restrict__ b, const float* __restrict__ c,
                 const float* __restrict__ coeff, float* __restrict__ out) {
    __shared__ float sCT[2][NC][1024];            // 56 KB: 2 slots x transposed coeff tile
    __shared__ float sMemb[ROWS_PER_BLOCK][NI][NM]; // 1.5 KB
    __shared__ float sPhi[ROWS_PER_BLOCK][64];      // 4 KB
    __shared__ float sRed[4][RPW][8];               // 0.5 KB cross-half combine

    const int tid  = threadIdx.x;
    const int row0 = blockIdx.x * ROWS_PER_BLOCK;
    const int wave = tid >> 6;
    const int lane = tid & 63;
    const int g = wave >> 1;    // row group 0..3
    const int h = wave & 1;     // rh half 0..1

    // ---- memberships: memb = 1/(1 + (((x-c)/a)^2)^b), 384 items ----
    if (tid < ROWS_PER_BLOCK * NI * NM) {
        int row = tid / (NI * NM);
        int rem = tid % (NI * NM);
        int j = rem >> 2, k = rem & 3;
        float xv = x[(row0 + row) * NI + j];
        float t = (xv - c[j * NM + k]) / a[j * NM + k];
        float dist = t * t;
        sMemb[row][j][k] = 1.0f / (1.0f + powf(dist, b[j * NM + k]));
    }
    __syncthreads();

    // ---- Phi table (16 rows x 64 rh) ----
    for (int idx = tid; idx < ROWS_PER_BLOCK * 64; idx += 512) {
        int row = idx >> 6, rh = idx & 63;
        sPhi[row][rh] = sMemb[row][0][(rh >> 4) & 3] *
                        sMemb[row][1][(rh >> 2) & 3] *
                        sMemb[row][2][rh & 3];
    }

    // ---- Plo for this lane's rlo, held in registers (one per owned row) ----
    float plo[RPW];
    {
        int d3 = (lane >> 4) & 3, d4 = (lane >> 2) & 3, d5 = lane & 3;
        #pragma unroll
        for (int r = 0; r < RPW; ++r) {
            int row = g * RPW + r;
            plo[r] = sMemb[row][3][d3] * sMemb[row][4][d4] * sMemb[row][5][d5];
        }
    }

    float acc[RPW][8];
    #pragma unroll
    for (int r = 0; r < RPW; ++r)
        #pragma unroll
        for (int i = 0; i < 8; ++i) acc[r][i] = 0.0f;

    __syncthreads();   // sPhi ready

    // ---- 2 phases: stage both slots (16 rh each), then compute ----
    for (int p = 0; p < 2; ++p) {
        if (p) __syncthreads();   // previous compute done before overwrite

        // stage: slot s covers rh [s*32 + p*16, +16) = rules [(s*32+p*16)*64, +1024)
        // flat coeff element index for linear idx is idx + (s+p)*7168  (coalesced)
        for (int idx = tid; idx < 2 * 7168; idx += 512) {
            int s   = (idx >= 7168) ? 1 : 0;
            int rem = idx - s * 7168;
            int rr  = rem / NC;
            int i   = rem - rr * NC;
            sCT[s][i][rr] = coeff[idx + (s + p) * 7168];
        }
        __syncthreads();

        // compute: this wave's slot = h, 16 rh values
        #pragma unroll 4
        for (int rhl = 0; rhl < 16; ++rhl) {
            const int rh = h * 32 + p * 16 + rhl;   // global rh for sPhi
            float cv[NC];
            #pragma unroll
            for (int i = 0; i < NC; ++i) cv[i] = sCT[h][i][rhl * 64 + lane];
            #pragma unroll
            for (int r = 0; r < RPW; ++r) {
                float w = sPhi[g * RPW + r][rh] * plo[r];
                acc[r][7] += w;
                #pragma unroll
                for (int i = 0; i < NC; ++i)
                    acc[r][i] = fmaf(w, cv[i], acc[r][i]);
            }
        }
    }

    // ---- 64-lane butterfly reduction (compile-time indices only) ----
    #pragma unroll
    for (int r = 0; r < RPW; ++r)
        #pragma unroll
        for (int i = 0; i < 8; ++i) {
            float v = acc[r][i];
            #pragma unroll
            for (int s = 1; s < 64; s <<= 1) v += __shfl_xor(v, s, 64);
            acc[r][i] = v;
        }

    // ---- combine the two rh-halves, finalize, store ----
    if (h == 1 && lane == 0) {
        #pragma unroll
        for (int r = 0; r < RPW; ++r)
            #pragma unroll
            for (int i = 0; i < 8; ++i) sRed[g][r][i] = acc[r][i];
    }
    __syncthreads();
    if (h == 0 && lane == 0) {
        #pragma unroll
        for (int r = 0; r < RPW; ++r) {
            int row = row0 + g * RPW + r;
            float den = acc[r][7] + sRed[g][r][7];
            float num = acc[r][6] + sRed[g][r][6];   // bias column (x_plus = 1)
            #pragma unroll
            for (int j = 0; j < NI; ++j)
                num = fmaf(acc[r][j] + sRed[g][r][j], x[row * NI + j], num);
            out[row] = num / fmaxf(den, 1e-12f);
        }
    }
}

extern "C" void kernel_launch(void* const* d_in, const int* in_sizes, int n_in,
                              void* d_out, int out_size, void* d_ws, size_t ws_size,
                              hipStream_t stream) {
    const float* x     = (const float*)d_in[0];
    const float* a     = (const float*)d_in[1];
    const float* b     = (const float*)d_in[2];
    const float* c     = (const float*)d_in[3];
    const float* coeff = (const float*)d_in[4];
    // d_in[5] = mf_indices: encoded exactly by the rh/rlo digit factorization.
    float* out = (float*)d_out;

    const int B = in_sizes[0] / NI;                 // 4096
    anfis_fused<<<dim3(B / ROWS_PER_BLOCK), dim3(512), 0, stream>>>(x, a, b, c, coeff, out);
}